// Round 1
// baseline (653.014 us; speedup 1.0000x reference)
//
#include <hip/hip_runtime.h>
#include <math.h>

#define BATCH 4096
#define D 512
#define NCLASS 1000
#define NCON 8
#define NTOT 8000   // NCLASS * NCON

#define BM 128
#define BN 128
#define BK 16
#define TM 8
#define TN 8

// ---------------------------------------------------------------------------
// Kernel 1: inv_norm[b] = 1 / ||image_encodings[b]||  (one wave per row)
// ---------------------------------------------------------------------------
__global__ __launch_bounds__(256) void rownorm_kernel(
    const float* __restrict__ x, float* __restrict__ inv_norm)
{
    const int row  = blockIdx.x * 4 + (threadIdx.x >> 6);
    const int lane = threadIdx.x & 63;
    const float4* x4 = (const float4*)(x + (size_t)row * D);
    float4 a = x4[lane];
    float4 b = x4[lane + 64];
    float s = a.x*a.x + a.y*a.y + a.z*a.z + a.w*a.w
            + b.x*b.x + b.y*b.y + b.z*b.z + b.w*b.w;
    #pragma unroll
    for (int off = 32; off; off >>= 1) s += __shfl_xor(s, off, 64);
    if (lane == 0) inv_norm[row] = 1.0f / sqrtf(s);
}

// ---------------------------------------------------------------------------
// Kernel 2: sims[b][n] = (A[b] . B[n]) * inv_norm[b]
// A: [BATCH, D] row-major, B: [NTOT, D] row-major (NT GEMM, both K-contig)
// fp32 vector-ALU SGEMM, 128x128 block tile, 8x8 per thread, BK=16
// ---------------------------------------------------------------------------
__global__ __launch_bounds__(256) void gemm_norm_kernel(
    const float* __restrict__ A, const float* __restrict__ B,
    const float* __restrict__ invn, float* __restrict__ C)
{
    __shared__ float As[BK][BM];
    __shared__ float Bs[BK][BN];

    const int tid = threadIdx.x;
    const int tx  = tid & 15;   // output col group (TN=8 cols each)
    const int ty  = tid >> 4;   // output row group (TM=8 rows each)
    const int m0  = blockIdx.y * BM;
    const int n0  = blockIdx.x * BN;

    // staging: thread t loads float4 at (row = t/4, col = (t%4)*4), rows +0 / +64
    const int lr = tid >> 2;          // 0..63
    const int lc = (tid & 3) << 2;    // 0,4,8,12

    float acc[TM][TN];
    #pragma unroll
    for (int i = 0; i < TM; ++i)
        #pragma unroll
        for (int j = 0; j < TN; ++j) acc[i][j] = 0.f;

    const int  nr0 = n0 + lr, nr1 = n0 + lr + 64;
    const bool bv0 = nr0 < NTOT, bv1 = nr1 < NTOT;
    const float* Arow0 = A + (size_t)(m0 + lr) * D + lc;
    const float* Arow1 = Arow0 + (size_t)64 * D;
    const float* Brow0 = B + (size_t)nr0 * D + lc;
    const float* Brow1 = Brow0 + (size_t)64 * D;

    for (int k0 = 0; k0 < D; k0 += BK) {
        float4 a0 = *(const float4*)(Arow0 + k0);
        float4 a1 = *(const float4*)(Arow1 + k0);
        float4 b0 = bv0 ? *(const float4*)(Brow0 + k0) : make_float4(0.f,0.f,0.f,0.f);
        float4 b1 = bv1 ? *(const float4*)(Brow1 + k0) : make_float4(0.f,0.f,0.f,0.f);

        __syncthreads();   // previous tile's readers done
        As[lc+0][lr]    = a0.x; As[lc+1][lr]    = a0.y; As[lc+2][lr]    = a0.z; As[lc+3][lr]    = a0.w;
        As[lc+0][lr+64] = a1.x; As[lc+1][lr+64] = a1.y; As[lc+2][lr+64] = a1.z; As[lc+3][lr+64] = a1.w;
        Bs[lc+0][lr]    = b0.x; Bs[lc+1][lr]    = b0.y; Bs[lc+2][lr]    = b0.z; Bs[lc+3][lr]    = b0.w;
        Bs[lc+0][lr+64] = b1.x; Bs[lc+1][lr+64] = b1.y; Bs[lc+2][lr+64] = b1.z; Bs[lc+3][lr+64] = b1.w;
        __syncthreads();

        #pragma unroll
        for (int kk = 0; kk < BK; ++kk) {
            float af[TM], bf[TN];
            *(float4*)&af[0] = *(const float4*)&As[kk][ty*TM];
            *(float4*)&af[4] = *(const float4*)&As[kk][ty*TM+4];
            *(float4*)&bf[0] = *(const float4*)&Bs[kk][tx*TN];
            *(float4*)&bf[4] = *(const float4*)&Bs[kk][tx*TN+4];
            #pragma unroll
            for (int i = 0; i < TM; ++i)
                #pragma unroll
                for (int j = 0; j < TN; ++j)
                    acc[i][j] = fmaf(af[i], bf[j], acc[i][j]);
        }
    }

    // epilogue: scale by inv_norm[row], store (col-range fully valid iff col < NTOT,
    // since NTOT % 8 == 0 and cols are multiples of 8)
    const int col = n0 + tx * TN;
    if (col < NTOT) {
        #pragma unroll
        for (int i = 0; i < TM; ++i) {
            const int row = m0 + ty * TM + i;
            const float s = invn[row];
            float4 o0, o1;
            o0.x = acc[i][0]*s; o0.y = acc[i][1]*s; o0.z = acc[i][2]*s; o0.w = acc[i][3]*s;
            o1.x = acc[i][4]*s; o1.y = acc[i][5]*s; o1.z = acc[i][6]*s; o1.w = acc[i][7]*s;
            float* Crow = C + (size_t)row * NTOT + col;
            *(float4*)Crow     = o0;
            *(float4*)(Crow+4) = o1;
        }
    }
}

// ---------------------------------------------------------------------------
// Kernel 3: per-row top-8 of sims[row][0..7999] -> weighted class votes ->
// argmax (first-index tie-break). One wave per row.
// ---------------------------------------------------------------------------
__global__ __launch_bounds__(256) void topk_vote_kernel(
    const float* __restrict__ sims, float* __restrict__ pred, float* __restrict__ conf)
{
    const int row  = blockIdx.x * 4 + (threadIdx.x >> 6);
    const int lane = threadIdx.x & 63;
    const float* s = sims + (size_t)row * NTOT;

    // lane-local sorted top-8 (desc; ties keep smaller index first since j increases)
    float v[8]; int ix[8];
    #pragma unroll
    for (int i = 0; i < 8; ++i) { v[i] = -INFINITY; ix[i] = 0x7fffffff; }

    for (int j = lane; j < NTOT; j += 64) {
        const float x = s[j];
        if (x > v[7]) {
            v[7] = x; ix[7] = j;
            #pragma unroll
            for (int p = 7; p > 0; --p) {
                if (v[p] > v[p-1]) {
                    float tv = v[p];  v[p] = v[p-1];  v[p-1] = tv;
                    int   ti = ix[p]; ix[p] = ix[p-1]; ix[p-1] = ti;
                }
            }
        }
    }

    // wave-merge: 8 rounds of butterfly arg-max over lane heads (ties -> smaller idx)
    float topv[8]; int topi[8];
    #pragma unroll
    for (int r = 0; r < 8; ++r) {
        float mv = v[0]; int mi = ix[0];
        #pragma unroll
        for (int off = 32; off; off >>= 1) {
            const float ov = __shfl_xor(mv, off, 64);
            const int   oi = __shfl_xor(mi, off, 64);
            if (ov > mv || (ov == mv && oi < mi)) { mv = ov; mi = oi; }
        }
        topv[r] = mv; topi[r] = mi;
        if (ix[0] == mi) {   // this lane's head won: pop (static-index shift)
            #pragma unroll
            for (int q = 0; q < 7; ++q) { v[q] = v[q+1]; ix[q] = ix[q+1]; }
            v[7] = -INFINITY; ix[7] = 0x7fffffff;
        }
    }
    (void)topv;

    // rank weights: w[r] = log1p(8-r) / sum  (same order/arith as reference)
    float w[8]; float z = 0.f;
    #pragma unroll
    for (int r = 0; r < 8; ++r) { w[r] = log1pf((float)(8 - r)); z += w[r]; }
    #pragma unroll
    for (int r = 0; r < 8; ++r) w[r] /= z;

    // votes per class (<= 8 distinct classes), argmax with smallest-index tie-break
    float best = -1.f; int bestc = 0x7fffffff;
    #pragma unroll
    for (int r = 0; r < 8; ++r) {
        const int cr = topi[r] >> 3;
        bool dup = false;
        #pragma unroll
        for (int q = 0; q < r; ++q) dup = dup || ((topi[q] >> 3) == cr);
        float vote = w[r];
        #pragma unroll
        for (int q = r + 1; q < 8; ++q) vote += ((topi[q] >> 3) == cr) ? w[q] : 0.f;
        if (!dup && (vote > best || (vote == best && cr < bestc))) { best = vote; bestc = cr; }
    }

    if (lane == 0) { pred[row] = (float)bestc; conf[row] = best; }
}

// ---------------------------------------------------------------------------
extern "C" void kernel_launch(void* const* d_in, const int* in_sizes, int n_in,
                              void* d_out, int out_size, void* d_ws, size_t ws_size,
                              hipStream_t stream) {
    (void)in_sizes; (void)n_in; (void)out_size; (void)ws_size;
    const float* img  = (const float*)d_in[0];  // [4096, 512]
    const float* desc = (const float*)d_in[1];  // [1000, 8, 512] -> [8000, 512]
    float* out  = (float*)d_out;
    float* pred = out;                 // [4096]
    float* conf = out + BATCH;         // [4096]
    float* sims = out + 2 * BATCH;     // [4096, 8000]
    float* invn = (float*)d_ws;        // 4096 floats scratch

    rownorm_kernel<<<BATCH / 4, 256, 0, stream>>>(img, invn);

    dim3 g((NTOT + BN - 1) / BN, BATCH / BM);   // 63 x 32
    gemm_norm_kernel<<<g, 256, 0, stream>>>(img, desc, invn, sims);

    topk_vote_kernel<<<BATCH / 4, 256, 0, stream>>>(sims, pred, conf);
}

// Round 3
// 408.118 us; speedup vs baseline: 1.6001x; 1.6001x over previous
//
#include <hip/hip_runtime.h>
#include <math.h>

#define BATCH 4096
#define D 512
#define NCLASS 1000
#define NCON 8
#define NTOT 8000        // NCLASS * NCON
#define NPAD 8064        // padded N for full 128-tiles (63 * 128)
#define KEXP 1536        // 3 * D  (hi|hi|lo x hi|lo|hi split)

typedef __attribute__((ext_vector_type(8))) short bf16x8;
typedef __attribute__((ext_vector_type(4))) float f32x4;

// float -> bf16 bits (round-to-nearest-even)
static __device__ __forceinline__ unsigned short f2bf(float f) {
    unsigned int u = __float_as_uint(f);
    unsigned int r = (u + 0x7fffu + ((u >> 16) & 1u)) >> 16;
    return (unsigned short)r;
}
static __device__ __forceinline__ float bf2f(unsigned short h) {
    return __uint_as_float(((unsigned int)h) << 16);
}

// ---------------------------------------------------------------------------
// prep_A: per row r of image_encodings: normalize (fp32), split to bf16 hi/lo,
// write A_c[r] = [hi(512) | hi(512) | lo(512)].  One wave per row.
// ---------------------------------------------------------------------------
__global__ __launch_bounds__(256) void prep_A_kernel(
    const float* __restrict__ x, unsigned short* __restrict__ Ac)
{
    const int row  = blockIdx.x * 4 + (threadIdx.x >> 6);
    const int lane = threadIdx.x & 63;
    const float4* x4 = (const float4*)(x + (size_t)row * D);
    float4 a = x4[lane];        // cols 4l .. 4l+3
    float4 b = x4[lane + 64];   // cols 256+4l ..
    float s = a.x*a.x + a.y*a.y + a.z*a.z + a.w*a.w
            + b.x*b.x + b.y*b.y + b.z*b.z + b.w*b.w;
    #pragma unroll
    for (int off = 32; off; off >>= 1) s += __shfl_xor(s, off, 64);
    const float inv = 1.0f / sqrtf(s);

    float av[4] = {a.x, a.y, a.z, a.w};
    float bv[4] = {b.x, b.y, b.z, b.w};
    ushort4 ha, la, hb, lb;
    unsigned short* pha = (unsigned short*)&ha; unsigned short* pla = (unsigned short*)&la;
    unsigned short* phb = (unsigned short*)&hb; unsigned short* plb = (unsigned short*)&lb;
    #pragma unroll
    for (int c = 0; c < 4; ++c) {
        float fa = av[c] * inv;
        unsigned short h = f2bf(fa);
        pha[c] = h; pla[c] = f2bf(fa - bf2f(h));
        float fb = bv[c] * inv;
        h = f2bf(fb);
        phb[c] = h; plb[c] = f2bf(fb - bf2f(h));
    }
    unsigned short* base = Ac + (size_t)row * KEXP;
    const int c0 = lane * 4;
    *(ushort4*)(base + c0)              = ha;   // hi @ [0:512)
    *(ushort4*)(base + 256 + c0)        = hb;
    *(ushort4*)(base + 512 + c0)        = ha;   // hi @ [512:1024)
    *(ushort4*)(base + 768 + c0)        = hb;
    *(ushort4*)(base + 1024 + c0)       = la;   // lo @ [1024:1536)
    *(ushort4*)(base + 1280 + c0)       = lb;
}

// ---------------------------------------------------------------------------
// prep_B: per row r of desc (flattened [8000][512]): split to bf16 hi/lo,
// write B_c[r] = [hi(512) | lo(512) | hi(512)]; rows 8000..8063 zeroed.
// ---------------------------------------------------------------------------
__global__ __launch_bounds__(256) void prep_B_kernel(
    const float* __restrict__ x, unsigned short* __restrict__ Bc)
{
    const int row  = blockIdx.x * 4 + (threadIdx.x >> 6);
    const int lane = threadIdx.x & 63;
    unsigned short* base = Bc + (size_t)row * KEXP;
    const int c0 = lane * 4;
    if (row < NTOT) {
        const float4* x4 = (const float4*)(x + (size_t)row * D);
        float4 a = x4[lane];
        float4 b = x4[lane + 64];
        float av[4] = {a.x, a.y, a.z, a.w};
        float bv[4] = {b.x, b.y, b.z, b.w};
        ushort4 ha, la, hb, lb;
        unsigned short* pha = (unsigned short*)&ha; unsigned short* pla = (unsigned short*)&la;
        unsigned short* phb = (unsigned short*)&hb; unsigned short* plb = (unsigned short*)&lb;
        #pragma unroll
        for (int c = 0; c < 4; ++c) {
            unsigned short h = f2bf(av[c]);
            pha[c] = h; pla[c] = f2bf(av[c] - bf2f(h));
            h = f2bf(bv[c]);
            phb[c] = h; plb[c] = f2bf(bv[c] - bf2f(h));
        }
        *(ushort4*)(base + c0)        = ha;   // hi @ [0:512)
        *(ushort4*)(base + 256 + c0)  = hb;
        *(ushort4*)(base + 512 + c0)  = la;   // lo @ [512:1024)
        *(ushort4*)(base + 768 + c0)  = lb;
        *(ushort4*)(base + 1024 + c0) = ha;   // hi @ [1024:1536)
        *(ushort4*)(base + 1280 + c0) = hb;
    } else {
        ushort4 z = make_ushort4(0,0,0,0);
        *(ushort4*)(base + c0)        = z;
        *(ushort4*)(base + 256 + c0)  = z;
        *(ushort4*)(base + 512 + c0)  = z;
        *(ushort4*)(base + 768 + c0)  = z;
        *(ushort4*)(base + 1024 + c0) = z;
        *(ushort4*)(base + 1280 + c0) = z;
    }
}

// ---------------------------------------------------------------------------
// bf16 MFMA GEMM (m97 structure): C[4096][8000] = A_c[4096][1536] . B_c^T
// 128x128 tile, BK=32, 4 waves (2x2 of 64x64), global_load_lds width 16,
// 8 ds_read_b128 + 16 mfma_f32_16x16x32_bf16 per K-step.
// ---------------------------------------------------------------------------
__global__ __launch_bounds__(256) void gemm_bf16_kernel(
    const unsigned short* __restrict__ A, const unsigned short* __restrict__ B,
    float* __restrict__ C)
{
    __shared__ short As[128 * 32];
    __shared__ short Bs[128 * 32];

    const int tid  = threadIdx.x;
    const int w    = tid >> 6;       // wave 0..3
    const int l    = tid & 63;
    const int wm   = w >> 1;         // wave row   (0..1)
    const int wn   = w & 1;          // wave col   (0..1)
    const int m0   = blockIdx.y * 128;
    const int n0   = blockIdx.x * 128;

    f32x4 acc[4][4];
    #pragma unroll
    for (int i = 0; i < 4; ++i)
        #pragma unroll
        for (int j = 0; j < 4; ++j) acc[i][j] = (f32x4){0.f, 0.f, 0.f, 0.f};

    // staging addresses: instr i covers rows (w*32 + i*16 + l/4), col8 = (l&3)*8
    const int srow = w * 32 + (l >> 2);
    const int scol = (l & 3) * 8;
    const unsigned short* gA0 = A + (size_t)(m0 + srow) * KEXP + scol;
    const unsigned short* gA1 = gA0 + (size_t)16 * KEXP;
    const unsigned short* gB0 = B + (size_t)(n0 + srow) * KEXP + scol;
    const unsigned short* gB1 = gB0 + (size_t)16 * KEXP;
    short* lA0 = &As[(w * 32) * 32];
    short* lA1 = &As[(w * 32 + 16) * 32];
    short* lB0 = &Bs[(w * 32) * 32];
    short* lB1 = &Bs[(w * 32 + 16) * 32];

    // fragment read offsets (lane l): row (l&15), k-chunk (l>>4)*8
    const int fro = (l & 15) * 32 + (l >> 4) * 8;

    for (int k0 = 0; k0 < KEXP; k0 += 32) {
        __syncthreads();   // previous iteration's readers done
        __builtin_amdgcn_global_load_lds(
            (const __attribute__((address_space(1))) void*)(gA0 + k0),
            (__attribute__((address_space(3))) void*)lA0, 16, 0, 0);
        __builtin_amdgcn_global_load_lds(
            (const __attribute__((address_space(1))) void*)(gA1 + k0),
            (__attribute__((address_space(3))) void*)lA1, 16, 0, 0);
        __builtin_amdgcn_global_load_lds(
            (const __attribute__((address_space(1))) void*)(gB0 + k0),
            (__attribute__((address_space(3))) void*)lB0, 16, 0, 0);
        __builtin_amdgcn_global_load_lds(
            (const __attribute__((address_space(1))) void*)(gB1 + k0),
            (__attribute__((address_space(3))) void*)lB1, 16, 0, 0);
        __syncthreads();   // compiler emits vmcnt(0) drain here

        bf16x8 a[4], b[4];
        #pragma unroll
        for (int i = 0; i < 4; ++i)
            a[i] = *(const bf16x8*)&As[(wm * 64 + i * 16) * 32 + fro];
        #pragma unroll
        for (int j = 0; j < 4; ++j)
            b[j] = *(const bf16x8*)&Bs[(wn * 64 + j * 16) * 32 + fro];

        #pragma unroll
        for (int i = 0; i < 4; ++i)
            #pragma unroll
            for (int j = 0; j < 4; ++j)
                acc[i][j] = __builtin_amdgcn_mfma_f32_16x16x32_bf16(
                    a[i], b[j], acc[i][j], 0, 0, 0);
    }

    // epilogue: C row = m0 + wm*64 + i*16 + (l>>4)*4 + r, col = n0 + wn*64 + j*16 + (l&15)
    #pragma unroll
    for (int i = 0; i < 4; ++i) {
        const int row = m0 + wm * 64 + i * 16 + (l >> 4) * 4;
        #pragma unroll
        for (int j = 0; j < 4; ++j) {
            const int col = n0 + wn * 64 + j * 16 + (l & 15);
            if (col < NTOT) {
                float* Cp = C + (size_t)row * NTOT + col;
                #pragma unroll
                for (int r = 0; r < 4; ++r) Cp[(size_t)r * NTOT] = acc[i][j][r];
            }
        }
    }
}

// ---------------------------------------------------------------------------
// topk + vote + argmax, one wave per row, float4 loads
// ---------------------------------------------------------------------------
__global__ __launch_bounds__(256) void topk_vote_kernel(
    const float* __restrict__ sims, float* __restrict__ pred, float* __restrict__ conf)
{
    const int row  = blockIdx.x * 4 + (threadIdx.x >> 6);
    const int lane = threadIdx.x & 63;
    const float4* s4 = (const float4*)(sims + (size_t)row * NTOT);

    float v[8]; int ix[8];
    #pragma unroll
    for (int i = 0; i < 8; ++i) { v[i] = -INFINITY; ix[i] = 0x7fffffff; }

    #define INS(val, idx)                                                     \
        if ((val) > v[7]) {                                                   \
            v[7] = (val); ix[7] = (idx);                                      \
            _Pragma("unroll")                                                 \
            for (int p = 7; p > 0; --p)                                       \
                if (v[p] > v[p-1]) {                                          \
                    float tv = v[p];  v[p] = v[p-1];  v[p-1] = tv;            \
                    int   ti = ix[p]; ix[p] = ix[p-1]; ix[p-1] = ti;          \
                }                                                             \
        }

    for (int i = 0; i < 32; ++i) {
        const int p4 = i * 64 + lane;
        if (p4 < NTOT / 4) {
            const float4 q = s4[p4];
            const float mx = fmaxf(fmaxf(q.x, q.y), fmaxf(q.z, q.w));
            if (mx > v[7]) {
                const int j = 4 * p4;
                INS(q.x, j); INS(q.y, j + 1); INS(q.z, j + 2); INS(q.w, j + 3);
            }
        }
    }
    #undef INS

    // wave-merge: 8 rounds of butterfly arg-max (ties -> smaller index)
    int topi[8];
    #pragma unroll
    for (int r = 0; r < 8; ++r) {
        float mv = v[0]; int mi = ix[0];
        #pragma unroll
        for (int off = 32; off; off >>= 1) {
            const float ov = __shfl_xor(mv, off, 64);
            const int   oi = __shfl_xor(mi, off, 64);
            if (ov > mv || (ov == mv && oi < mi)) { mv = ov; mi = oi; }
        }
        topi[r] = mi;
        if (ix[0] == mi) {
            #pragma unroll
            for (int q = 0; q < 7; ++q) { v[q] = v[q+1]; ix[q] = ix[q+1]; }
            v[7] = -INFINITY; ix[7] = 0x7fffffff;
        }
    }

    float w[8]; float z = 0.f;
    #pragma unroll
    for (int r = 0; r < 8; ++r) { w[r] = log1pf((float)(8 - r)); z += w[r]; }
    #pragma unroll
    for (int r = 0; r < 8; ++r) w[r] /= z;

    float best = -1.f; int bestc = 0x7fffffff;
    #pragma unroll
    for (int r = 0; r < 8; ++r) {
        const int cr = topi[r] >> 3;
        bool dup = false;
        #pragma unroll
        for (int q = 0; q < r; ++q) dup = dup || ((topi[q] >> 3) == cr);
        float vote = w[r];
        #pragma unroll
        for (int q = r + 1; q < 8; ++q) vote += ((topi[q] >> 3) == cr) ? w[q] : 0.f;
        if (!dup && (vote > best || (vote == best && cr < bestc))) { best = vote; bestc = cr; }
    }

    if (lane == 0) { pred[row] = (float)bestc; conf[row] = best; }
}

// ---------------------------------------------------------------------------
// Fallback fp32 path (used only if ws_size too small for bf16 split buffers)
// ---------------------------------------------------------------------------
__global__ __launch_bounds__(256) void rownorm_kernel(
    const float* __restrict__ x, float* __restrict__ inv_norm)
{
    const int row  = blockIdx.x * 4 + (threadIdx.x >> 6);
    const int lane = threadIdx.x & 63;
    const float4* x4 = (const float4*)(x + (size_t)row * D);
    float4 a = x4[lane];
    float4 b = x4[lane + 64];
    float s = a.x*a.x + a.y*a.y + a.z*a.z + a.w*a.w
            + b.x*b.x + b.y*b.y + b.z*b.z + b.w*b.w;
    #pragma unroll
    for (int off = 32; off; off >>= 1) s += __shfl_xor(s, off, 64);
    if (lane == 0) inv_norm[row] = 1.0f / sqrtf(s);
}

__global__ __launch_bounds__(256) void gemm_norm_kernel(
    const float* __restrict__ A, const float* __restrict__ B,
    const float* __restrict__ invn, float* __restrict__ C)
{
    __shared__ float As[16][128];
    __shared__ float Bs[16][128];
    const int tid = threadIdx.x;
    const int tx  = tid & 15;
    const int ty  = tid >> 4;
    const int m0  = blockIdx.y * 128;
    const int n0  = blockIdx.x * 128;
    const int lr = tid >> 2;
    const int lc = (tid & 3) << 2;
    float acc[8][8];
    #pragma unroll
    for (int i = 0; i < 8; ++i)
        #pragma unroll
        for (int j = 0; j < 8; ++j) acc[i][j] = 0.f;
    const int  nr0 = n0 + lr, nr1 = n0 + lr + 64;
    const bool bv0 = nr0 < NTOT, bv1 = nr1 < NTOT;
    const float* Arow0 = A + (size_t)(m0 + lr) * D + lc;
    const float* Arow1 = Arow0 + (size_t)64 * D;
    const float* Brow0 = B + (size_t)nr0 * D + lc;
    const float* Brow1 = Brow0 + (size_t)64 * D;
    for (int k0 = 0; k0 < D; k0 += 16) {
        float4 a0 = *(const float4*)(Arow0 + k0);
        float4 a1 = *(const float4*)(Arow1 + k0);
        float4 b0 = bv0 ? *(const float4*)(Brow0 + k0) : make_float4(0.f,0.f,0.f,0.f);
        float4 b1 = bv1 ? *(const float4*)(Brow1 + k0) : make_float4(0.f,0.f,0.f,0.f);
        __syncthreads();
        As[lc+0][lr]    = a0.x; As[lc+1][lr]    = a0.y; As[lc+2][lr]    = a0.z; As[lc+3][lr]    = a0.w;
        As[lc+0][lr+64] = a1.x; As[lc+1][lr+64] = a1.y; As[lc+2][lr+64] = a1.z; As[lc+3][lr+64] = a1.w;
        Bs[lc+0][lr]    = b0.x; Bs[lc+1][lr]    = b0.y; Bs[lc+2][lr]    = b0.z; Bs[lc+3][lr]    = b0.w;
        Bs[lc+0][lr+64] = b1.x; Bs[lc+1][lr+64] = b1.y; Bs[lc+2][lr+64] = b1.z; Bs[lc+3][lr+64] = b1.w;
        __syncthreads();
        #pragma unroll
        for (int kk = 0; kk < 16; ++kk) {
            float af[8], bf[8];
            *(float4*)&af[0] = *(const float4*)&As[kk][ty*8];
            *(float4*)&af[4] = *(const float4*)&As[kk][ty*8+4];
            *(float4*)&bf[0] = *(const float4*)&Bs[kk][tx*8];
            *(float4*)&bf[4] = *(const float4*)&Bs[kk][tx*8+4];
            #pragma unroll
            for (int i = 0; i < 8; ++i)
                #pragma unroll
                for (int j = 0; j < 8; ++j)
                    acc[i][j] = fmaf(af[i], bf[j], acc[i][j]);
        }
    }
    const int col = n0 + tx * 8;
    if (col < NTOT) {
        #pragma unroll
        for (int i = 0; i < 8; ++i) {
            const int row = m0 + ty * 8 + i;
            const float s = invn[row];
            float4 o0, o1;
            o0.x = acc[i][0]*s; o0.y = acc[i][1]*s; o0.z = acc[i][2]*s; o0.w = acc[i][3]*s;
            o1.x = acc[i][4]*s; o1.y = acc[i][5]*s; o1.z = acc[i][6]*s; o1.w = acc[i][7]*s;
            float* Crow = C + (size_t)row * NTOT + col;
            *(float4*)Crow     = o0;
            *(float4*)(Crow+4) = o1;
        }
    }
}

// ---------------------------------------------------------------------------
extern "C" void kernel_launch(void* const* d_in, const int* in_sizes, int n_in,
                              void* d_out, int out_size, void* d_ws, size_t ws_size,
                              hipStream_t stream) {
    (void)in_sizes; (void)n_in; (void)out_size;
    const float* img  = (const float*)d_in[0];  // [4096, 512]
    const float* desc = (const float*)d_in[1];  // [1000, 8, 512] -> [8000, 512]
    float* out  = (float*)d_out;
    float* pred = out;                 // [4096]
    float* conf = out + BATCH;         // [4096]
    float* sims = out + 2 * BATCH;     // [4096, 8000]

    const size_t szA = (size_t)BATCH * KEXP * sizeof(unsigned short);   // 12.6 MB
    const size_t szB = (size_t)NPAD  * KEXP * sizeof(unsigned short);   // 24.8 MB

    if (ws_size >= szA + szB) {
        unsigned short* Ac = (unsigned short*)d_ws;
        unsigned short* Bc = (unsigned short*)((char*)d_ws + szA);

        prep_A_kernel<<<BATCH / 4, 256, 0, stream>>>(img, Ac);
        prep_B_kernel<<<NPAD / 4, 256, 0, stream>>>(desc, Bc);

        dim3 g(NPAD / 128, BATCH / 128);   // 63 x 32
        gemm_bf16_kernel<<<g, 256, 0, stream>>>(Ac, Bc, sims);
    } else {
        float* invn = (float*)d_ws;
        rownorm_kernel<<<BATCH / 4, 256, 0, stream>>>(img, invn);
        dim3 g((NTOT + 127) / 128, BATCH / 128);
        gemm_norm_kernel<<<g, 256, 0, stream>>>(img, desc, invn, sims);
    }

    topk_vote_kernel<<<BATCH / 4, 256, 0, stream>>>(sims, pred, conf);
}

// Round 6
// 287.405 us; speedup vs baseline: 2.2721x; 1.4200x over previous
//
#include <hip/hip_runtime.h>
#include <math.h>

#define BATCH 4096
#define D 512
#define NCLASS 1000
#define NCON 8
#define NTOT 8000        // NCLASS * NCON
#define NPAD 8192        // padded N: 64 tiles of 128 (clean 8-XCD swizzle)
#define KH 1024          // hi(512) | lo(512) row length

typedef __attribute__((ext_vector_type(8))) short bf16x8;
typedef __attribute__((ext_vector_type(4))) float f32x4;

// float -> bf16 bits (round-to-nearest-even)
static __device__ __forceinline__ unsigned short f2bf(float f) {
    unsigned int u = __float_as_uint(f);
    unsigned int r = (u + 0x7fffu + ((u >> 16) & 1u)) >> 16;
    return (unsigned short)r;
}
static __device__ __forceinline__ float bf2f(unsigned short h) {
    return __uint_as_float(((unsigned int)h) << 16);
}

// ---------------------------------------------------------------------------
// prep_A: normalize row (fp32), split to bf16 hi/lo, write A_c[r] = [hi|lo]
// ---------------------------------------------------------------------------
__global__ __launch_bounds__(256) void prep_A_kernel(
    const float* __restrict__ x, unsigned short* __restrict__ Ac)
{
    const int row  = blockIdx.x * 4 + (threadIdx.x >> 6);
    const int lane = threadIdx.x & 63;
    const float4* x4 = (const float4*)(x + (size_t)row * D);
    float4 a = x4[lane];        // cols 4l .. 4l+3
    float4 b = x4[lane + 64];   // cols 256+4l ..
    float s = a.x*a.x + a.y*a.y + a.z*a.z + a.w*a.w
            + b.x*b.x + b.y*b.y + b.z*b.z + b.w*b.w;
    #pragma unroll
    for (int off = 32; off; off >>= 1) s += __shfl_xor(s, off, 64);
    const float inv = 1.0f / sqrtf(s);

    float av[4] = {a.x, a.y, a.z, a.w};
    float bv[4] = {b.x, b.y, b.z, b.w};
    ushort4 ha, la, hb, lb;
    unsigned short* pha = (unsigned short*)&ha; unsigned short* pla = (unsigned short*)&la;
    unsigned short* phb = (unsigned short*)&hb; unsigned short* plb = (unsigned short*)&lb;
    #pragma unroll
    for (int c = 0; c < 4; ++c) {
        float fa = av[c] * inv;
        unsigned short h = f2bf(fa);
        pha[c] = h; pla[c] = f2bf(fa - bf2f(h));
        float fb = bv[c] * inv;
        h = f2bf(fb);
        phb[c] = h; plb[c] = f2bf(fb - bf2f(h));
    }
    unsigned short* base = Ac + (size_t)row * KH;
    const int c0 = lane * 4;
    *(ushort4*)(base + c0)        = ha;   // hi  [0:512)
    *(ushort4*)(base + 256 + c0)  = hb;
    *(ushort4*)(base + 512 + c0)  = la;   // lo  [512:1024)
    *(ushort4*)(base + 768 + c0)  = lb;
}

// ---------------------------------------------------------------------------
// prep_B: split to bf16 hi/lo, write B_c[r] = [hi|lo]; rows >= NTOT zeroed
// ---------------------------------------------------------------------------
__global__ __launch_bounds__(256) void prep_B_kernel(
    const float* __restrict__ x, unsigned short* __restrict__ Bc)
{
    const int row  = blockIdx.x * 4 + (threadIdx.x >> 6);
    const int lane = threadIdx.x & 63;
    unsigned short* base = Bc + (size_t)row * KH;
    const int c0 = lane * 4;
    if (row < NTOT) {
        const float4* x4 = (const float4*)(x + (size_t)row * D);
        float4 a = x4[lane];
        float4 b = x4[lane + 64];
        float av[4] = {a.x, a.y, a.z, a.w};
        float bv[4] = {b.x, b.y, b.z, b.w};
        ushort4 ha, la, hb, lb;
        unsigned short* pha = (unsigned short*)&ha; unsigned short* pla = (unsigned short*)&la;
        unsigned short* phb = (unsigned short*)&hb; unsigned short* plb = (unsigned short*)&lb;
        #pragma unroll
        for (int c = 0; c < 4; ++c) {
            unsigned short h = f2bf(av[c]);
            pha[c] = h; pla[c] = f2bf(av[c] - bf2f(h));
            h = f2bf(bv[c]);
            phb[c] = h; plb[c] = f2bf(bv[c] - bf2f(h));
        }
        *(ushort4*)(base + c0)        = ha;
        *(ushort4*)(base + 256 + c0)  = hb;
        *(ushort4*)(base + 512 + c0)  = la;
        *(ushort4*)(base + 768 + c0)  = lb;
    } else {
        ushort4 z = make_ushort4(0,0,0,0);
        *(ushort4*)(base + c0)        = z;
        *(ushort4*)(base + 256 + c0)  = z;
        *(ushort4*)(base + 512 + c0)  = z;
        *(ushort4*)(base + 768 + c0)  = z;
    }
}

// ---------------------------------------------------------------------------
// bf16x3-split MFMA GEMM, pair layout: per K-step stage Ah,Al,Bh,Bl tiles
// (128x32 each) and do acc += Ah.Bh + Ah.Bl + Al.Bh  (48 MFMA / K-step).
// XCD-chunked swizzle: XCD x owns bx in [8x,8x+8), iterated bx-fastest.
// ---------------------------------------------------------------------------
__global__ __launch_bounds__(256) void gemm_bf16_kernel(
    const unsigned short* __restrict__ A, const unsigned short* __restrict__ B,
    float* __restrict__ C)
{
    __shared__ short sAh[128 * 32];
    __shared__ short sAl[128 * 32];
    __shared__ short sBh[128 * 32];
    __shared__ short sBl[128 * 32];

    const int tid  = threadIdx.x;
    const int w    = tid >> 6;       // wave 0..3
    const int l    = tid & 63;
    const int wm   = w >> 1;
    const int wn   = w & 1;

    // XCD-aware swizzle: 2048 blocks, xcd = bid%8 gets 8-column chunk
    const int bid = blockIdx.x;
    const int xcd = bid & 7;
    const int loc = bid >> 3;               // 0..255
    const int bx  = xcd * 8 + (loc & 7);    // 0..63
    const int by  = loc >> 3;               // 0..31
    const int m0  = by * 128;
    const int n0  = bx * 128;

    f32x4 acc[4][4];
    #pragma unroll
    for (int i = 0; i < 4; ++i)
        #pragma unroll
        for (int j = 0; j < 4; ++j) acc[i][j] = (f32x4){0.f, 0.f, 0.f, 0.f};

    const int srow = w * 32 + (l >> 2);
    const int scol = (l & 3) * 8;
    const unsigned short* gA0 = A + (size_t)(m0 + srow) * KH + scol;   // hi
    const unsigned short* gA1 = gA0 + (size_t)16 * KH;
    const unsigned short* gB0 = B + (size_t)(n0 + srow) * KH + scol;
    const unsigned short* gB1 = gB0 + (size_t)16 * KH;
    short* lAh0 = &sAh[(w * 32) * 32];      short* lAh1 = &sAh[(w * 32 + 16) * 32];
    short* lAl0 = &sAl[(w * 32) * 32];      short* lAl1 = &sAl[(w * 32 + 16) * 32];
    short* lBh0 = &sBh[(w * 32) * 32];      short* lBh1 = &sBh[(w * 32 + 16) * 32];
    short* lBl0 = &sBl[(w * 32) * 32];      short* lBl1 = &sBl[(w * 32 + 16) * 32];

    const int fro = (l & 15) * 32 + (l >> 4) * 8;

    for (int k0 = 0; k0 < D; k0 += 32) {
        __syncthreads();
        __builtin_amdgcn_global_load_lds((const __attribute__((address_space(1))) void*)(gA0 + k0),
            (__attribute__((address_space(3))) void*)lAh0, 16, 0, 0);
        __builtin_amdgcn_global_load_lds((const __attribute__((address_space(1))) void*)(gA1 + k0),
            (__attribute__((address_space(3))) void*)lAh1, 16, 0, 0);
        __builtin_amdgcn_global_load_lds((const __attribute__((address_space(1))) void*)(gA0 + 512 + k0),
            (__attribute__((address_space(3))) void*)lAl0, 16, 0, 0);
        __builtin_amdgcn_global_load_lds((const __attribute__((address_space(1))) void*)(gA1 + 512 + k0),
            (__attribute__((address_space(3))) void*)lAl1, 16, 0, 0);
        __builtin_amdgcn_global_load_lds((const __attribute__((address_space(1))) void*)(gB0 + k0),
            (__attribute__((address_space(3))) void*)lBh0, 16, 0, 0);
        __builtin_amdgcn_global_load_lds((const __attribute__((address_space(1))) void*)(gB1 + k0),
            (__attribute__((address_space(3))) void*)lBh1, 16, 0, 0);
        __builtin_amdgcn_global_load_lds((const __attribute__((address_space(1))) void*)(gB0 + 512 + k0),
            (__attribute__((address_space(3))) void*)lBl0, 16, 0, 0);
        __builtin_amdgcn_global_load_lds((const __attribute__((address_space(1))) void*)(gB1 + 512 + k0),
            (__attribute__((address_space(3))) void*)lBl1, 16, 0, 0);
        __syncthreads();

        bf16x8 ah[4], al[4], bh[4], bl[4];
        #pragma unroll
        for (int i = 0; i < 4; ++i) {
            ah[i] = *(const bf16x8*)&sAh[(wm * 64 + i * 16) * 32 + fro];
            al[i] = *(const bf16x8*)&sAl[(wm * 64 + i * 16) * 32 + fro];
        }
        #pragma unroll
        for (int j = 0; j < 4; ++j) {
            bh[j] = *(const bf16x8*)&sBh[(wn * 64 + j * 16) * 32 + fro];
            bl[j] = *(const bf16x8*)&sBl[(wn * 64 + j * 16) * 32 + fro];
        }

        #pragma unroll
        for (int i = 0; i < 4; ++i)
            #pragma unroll
            for (int j = 0; j < 4; ++j) {
                acc[i][j] = __builtin_amdgcn_mfma_f32_16x16x32_bf16(ah[i], bh[j], acc[i][j], 0, 0, 0);
                acc[i][j] = __builtin_amdgcn_mfma_f32_16x16x32_bf16(ah[i], bl[j], acc[i][j], 0, 0, 0);
                acc[i][j] = __builtin_amdgcn_mfma_f32_16x16x32_bf16(al[i], bh[j], acc[i][j], 0, 0, 0);
            }
    }

    #pragma unroll
    for (int i = 0; i < 4; ++i) {
        const int row = m0 + wm * 64 + i * 16 + (l >> 4) * 4;
        #pragma unroll
        for (int j = 0; j < 4; ++j) {
            const int col = n0 + wn * 64 + j * 16 + (l & 15);
            if (col < NTOT) {
                float* Cp = C + (size_t)row * NTOT + col;
                #pragma unroll
                for (int r = 0; r < 4; ++r) Cp[(size_t)r * NTOT] = acc[i][j][r];
            }
        }
    }
}

// ---------------------------------------------------------------------------
// topk + vote + argmax: ONE BLOCK (4 waves) per row.
// per-thread top-8 over ~31 candidates -> wave butterfly merge -> LDS merge.
// ---------------------------------------------------------------------------
__global__ __launch_bounds__(256) void topk_vote_kernel(
    const float* __restrict__ sims, float* __restrict__ pred, float* __restrict__ conf)
{
    const int row  = blockIdx.x;
    const int tid  = threadIdx.x;
    const int wv   = tid >> 6;
    const int lane = tid & 63;
    const float4* s4 = (const float4*)(sims + (size_t)row * NTOT);

    float v[8]; int ix[8];
    #pragma unroll
    for (int i = 0; i < 8; ++i) { v[i] = -INFINITY; ix[i] = 0x7fffffff; }

    #define INS(val, idx)                                                     \
        if ((val) > v[7]) {                                                   \
            v[7] = (val); ix[7] = (idx);                                      \
            _Pragma("unroll")                                                 \
            for (int p = 7; p > 0; --p)                                       \
                if (v[p] > v[p-1]) {                                          \
                    float tv = v[p];  v[p] = v[p-1];  v[p-1] = tv;            \
                    int   ti = ix[p]; ix[p] = ix[p-1]; ix[p-1] = ti;          \
                }                                                             \
        }

    for (int p = tid; p < NTOT / 4; p += 256) {
        const float4 q = s4[p];
        const float mx = fmaxf(fmaxf(q.x, q.y), fmaxf(q.z, q.w));
        if (mx > v[7]) {
            const int j = 4 * p;
            INS(q.x, j); INS(q.y, j + 1); INS(q.z, j + 2); INS(q.w, j + 3);
        }
    }
    #undef INS

    // wave-level butterfly merge: 8 rounds (ties -> smaller index)
    float topv[8]; int topi[8];
    #pragma unroll
    for (int r = 0; r < 8; ++r) {
        float mv = v[0]; int mi = ix[0];
        #pragma unroll
        for (int off = 32; off; off >>= 1) {
            const float ov = __shfl_xor(mv, off, 64);
            const int   oi = __shfl_xor(mi, off, 64);
            if (ov > mv || (ov == mv && oi < mi)) { mv = ov; mi = oi; }
        }
        topv[r] = mv; topi[r] = mi;
        if (ix[0] == mi) {
            #pragma unroll
            for (int q = 0; q < 7; ++q) { v[q] = v[q+1]; ix[q] = ix[q+1]; }
            v[7] = -INFINITY; ix[7] = 0x7fffffff;
        }
    }

    // cross-wave merge via LDS: each wave's lane 0 writes its 8 pairs
    __shared__ float lv[32];
    __shared__ int   li[32];
    if (lane == 0) {
        #pragma unroll
        for (int r = 0; r < 8; ++r) { lv[wv * 8 + r] = topv[r]; li[wv * 8 + r] = topi[r]; }
    }
    __syncthreads();

    if (wv == 0) {
        float mv2 = -INFINITY; int mi2 = 0x7fffffff;
        if (lane < 32) { mv2 = lv[lane]; mi2 = li[lane]; }

        float fv[8]; int fi[8];
        #pragma unroll
        for (int r = 0; r < 8; ++r) {
            float m = mv2; int mi = mi2;
            #pragma unroll
            for (int off = 32; off; off >>= 1) {
                const float ov = __shfl_xor(m, off, 64);
                const int   oi = __shfl_xor(mi, off, 64);
                if (ov > m || (ov == m && oi < mi)) { m = ov; mi = oi; }
            }
            fv[r] = m; fi[r] = mi;
            if (mi2 == mi) { mv2 = -INFINITY; mi2 = 0x7fffffff; }
        }
        (void)fv;

        float w[8]; float z = 0.f;
        #pragma unroll
        for (int r = 0; r < 8; ++r) { w[r] = log1pf((float)(8 - r)); z += w[r]; }
        #pragma unroll
        for (int r = 0; r < 8; ++r) w[r] /= z;

        float best = -1.f; int bestc = 0x7fffffff;
        #pragma unroll
        for (int r = 0; r < 8; ++r) {
            const int cr = fi[r] >> 3;
            bool dup = false;
            #pragma unroll
            for (int q = 0; q < r; ++q) dup = dup || ((fi[q] >> 3) == cr);
            float vote = w[r];
            #pragma unroll
            for (int q = r + 1; q < 8; ++q) vote += ((fi[q] >> 3) == cr) ? w[q] : 0.f;
            if (!dup && (vote > best || (vote == best && cr < bestc))) { best = vote; bestc = cr; }
        }

        if (lane == 0) { pred[row] = (float)bestc; conf[row] = best; }
    }
}

// ---------------------------------------------------------------------------
// Fallback fp32 path (only if ws_size too small)
// ---------------------------------------------------------------------------
__global__ __launch_bounds__(256) void rownorm_kernel(
    const float* __restrict__ x, float* __restrict__ inv_norm)
{
    const int row  = blockIdx.x * 4 + (threadIdx.x >> 6);
    const int lane = threadIdx.x & 63;
    const float4* x4 = (const float4*)(x + (size_t)row * D);
    float4 a = x4[lane];
    float4 b = x4[lane + 64];
    float s = a.x*a.x + a.y*a.y + a.z*a.z + a.w*a.w
            + b.x*b.x + b.y*b.y + b.z*b.z + b.w*b.w;
    #pragma unroll
    for (int off = 32; off; off >>= 1) s += __shfl_xor(s, off, 64);
    if (lane == 0) inv_norm[row] = 1.0f / sqrtf(s);
}

__global__ __launch_bounds__(256) void gemm_norm_kernel(
    const float* __restrict__ A, const float* __restrict__ B,
    const float* __restrict__ invn, float* __restrict__ C)
{
    __shared__ float As[16][128];
    __shared__ float Bs[16][128];
    const int tid = threadIdx.x;
    const int tx  = tid & 15;
    const int ty  = tid >> 4;
    const int m0  = blockIdx.y * 128;
    const int n0  = blockIdx.x * 128;
    const int lr = tid >> 2;
    const int lc = (tid & 3) << 2;
    float acc[8][8];
    #pragma unroll
    for (int i = 0; i < 8; ++i)
        #pragma unroll
        for (int j = 0; j < 8; ++j) acc[i][j] = 0.f;
    const int  nr0 = n0 + lr, nr1 = n0 + lr + 64;
    const bool bv0 = nr0 < NTOT, bv1 = nr1 < NTOT;
    const float* Arow0 = A + (size_t)(m0 + lr) * D + lc;
    const float* Arow1 = Arow0 + (size_t)64 * D;
    const float* Brow0 = B + (size_t)nr0 * D + lc;
    const float* Brow1 = Brow0 + (size_t)64 * D;
    for (int k0 = 0; k0 < D; k0 += 16) {
        float4 a0 = *(const float4*)(Arow0 + k0);
        float4 a1 = *(const float4*)(Arow1 + k0);
        float4 b0 = bv0 ? *(const float4*)(Brow0 + k0) : make_float4(0.f,0.f,0.f,0.f);
        float4 b1 = bv1 ? *(const float4*)(Brow1 + k0) : make_float4(0.f,0.f,0.f,0.f);
        __syncthreads();
        As[lc+0][lr]    = a0.x; As[lc+1][lr]    = a0.y; As[lc+2][lr]    = a0.z; As[lc+3][lr]    = a0.w;
        As[lc+0][lr+64] = a1.x; As[lc+1][lr+64] = a1.y; As[lc+2][lr+64] = a1.z; As[lc+3][lr+64] = a1.w;
        Bs[lc+0][lr]    = b0.x; Bs[lc+1][lr]    = b0.y; Bs[lc+2][lr]    = b0.z; Bs[lc+3][lr]    = b0.w;
        Bs[lc+0][lr+64] = b1.x; Bs[lc+1][lr+64] = b1.y; Bs[lc+2][lr+64] = b1.z; Bs[lc+3][lr+64] = b1.w;
        __syncthreads();
        #pragma unroll
        for (int kk = 0; kk < 16; ++kk) {
            float af[8], bf[8];
            *(float4*)&af[0] = *(const float4*)&As[kk][ty*8];
            *(float4*)&af[4] = *(const float4*)&As[kk][ty*8+4];
            *(float4*)&bf[0] = *(const float4*)&Bs[kk][tx*8];
            *(float4*)&bf[4] = *(const float4*)&Bs[kk][tx*8+4];
            #pragma unroll
            for (int i = 0; i < 8; ++i)
                #pragma unroll
                for (int j = 0; j < 8; ++j)
                    acc[i][j] = fmaf(af[i], bf[j], acc[i][j]);
        }
    }
    const int col = n0 + tx * 8;
    if (col < NTOT) {
        #pragma unroll
        for (int i = 0; i < 8; ++i) {
            const int row = m0 + ty * 8 + i;
            const float s = invn[row];
            float4 o0, o1;
            o0.x = acc[i][0]*s; o0.y = acc[i][1]*s; o0.z = acc[i][2]*s; o0.w = acc[i][3]*s;
            o1.x = acc[i][4]*s; o1.y = acc[i][5]*s; o1.z = acc[i][6]*s; o1.w = acc[i][7]*s;
            float* Crow = C + (size_t)row * NTOT + col;
            *(float4*)Crow     = o0;
            *(float4*)(Crow+4) = o1;
        }
    }
}

// ---------------------------------------------------------------------------
extern "C" void kernel_launch(void* const* d_in, const int* in_sizes, int n_in,
                              void* d_out, int out_size, void* d_ws, size_t ws_size,
                              hipStream_t stream) {
    (void)in_sizes; (void)n_in; (void)out_size;
    const float* img  = (const float*)d_in[0];  // [4096, 512]
    const float* desc = (const float*)d_in[1];  // [1000, 8, 512] -> [8000, 512]
    float* out  = (float*)d_out;
    float* pred = out;                 // [4096]
    float* conf = out + BATCH;         // [4096]
    float* sims = out + 2 * BATCH;     // [4096, 8000]

    const size_t szA = (size_t)BATCH * KH * sizeof(unsigned short);   // 8.4 MB
    const size_t szB = (size_t)NPAD  * KH * sizeof(unsigned short);   // 16.8 MB

    if (ws_size >= szA + szB) {
        unsigned short* Ac = (unsigned short*)d_ws;
        unsigned short* Bc = (unsigned short*)((char*)d_ws + szA);

        prep_A_kernel<<<BATCH / 4, 256, 0, stream>>>(img, Ac);
        prep_B_kernel<<<NPAD / 4, 256, 0, stream>>>(desc, Bc);

        gemm_bf16_kernel<<<(NPAD / 128) * (BATCH / 128), 256, 0, stream>>>(Ac, Bc, sims);
    } else {
        float* invn = (float*)d_ws;
        rownorm_kernel<<<BATCH / 4, 256, 0, stream>>>(img, invn);
        dim3 g((NTOT + 127) / 128, BATCH / 128);
        gemm_norm_kernel<<<g, 256, 0, stream>>>(img, desc, invn, sims);
    }

    topk_vote_kernel<<<BATCH, 256, 0, stream>>>(sims, pred, conf);
}